// Round 6
// baseline (1846.396 us; speedup 1.0000x reference)
//
#include <hip/hip_runtime.h>
#include <math.h>

#define WAYS 5
#define NQN 4096
#define NBATCH (NQN*WAYS)

// workspace float offsets
#define WS_SC 0         // 5*25*64 spt centered*rinv (l2-normalized) [w][i][c]
#define WS_RS 8000      // 125 spt inv l2 norms
#define WS_SP 8125      // 125 spt proj
#define WS_QR 8250      // 102400 qry inv l2 norm [q][j]
#define WS_TP 110650    // 102400 qry proj [q][j]
#define WS_QN 213052    // 4096*25*64 qry centered*rinv (l2-normalized) [q][j][c] (16B aligned)

// wave-level phase fence: DS ops of one wave complete in order; waitcnt + compiler barrier
#define WSYNC() do { asm volatile("s_waitcnt lgkmcnt(0)" ::: "memory"); __builtin_amdgcn_wave_barrier(); } while(0)

__global__ void prep_spt(const float* __restrict__ spt, const float* __restrict__ proj_w,
                         const float* __restrict__ proj_b, float* __restrict__ ws) {
    int tid = threadIdx.x;
    if (tid >= 125) return;
    int w = tid / 25, i = tid % 25;
    const float* base = spt + w * 1600 + i;
    float s = 0.f;
    for (int c = 0; c < 64; c++) s += base[c * 25];
    float m = s * (1.f / 64.f);
    float ss = 0.f, pj = 0.f;
    for (int c = 0; c < 64; c++) {
        float v = base[c * 25] - m;
        ss += v * v; pj += v * proj_w[c];
    }
    float rinv = rsqrtf(ss + 1e-6f);
    for (int c = 0; c < 64; c++)
        ws[WS_SC + (w * 25 + i) * 64 + c] = (base[c * 25] - m) * rinv;
    ws[WS_RS + w * 25 + i] = rinv;
    ws[WS_SP + w * 25 + i] = pj + proj_b[0];
}

__global__ void prep_qry(const float* __restrict__ qry, const float* __restrict__ proj_w,
                         const float* __restrict__ proj_b, float* __restrict__ ws) {
    int idx = blockIdx.x * 256 + threadIdx.x;
    if (idx >= NQN * 25) return;
    int q = idx / 25, j = idx % 25;
    const float* base = qry + q * 1600 + j;
    float s = 0.f;
    for (int c = 0; c < 64; c++) s += base[c * 25];
    float m = s * (1.f / 64.f);
    float ss = 0.f, pj = 0.f;
    for (int c = 0; c < 64; c++) {
        float v = base[c * 25] - m;
        ss += v * v; pj += v * proj_w[c];
    }
    float rinv = rsqrtf(ss + 1e-6f);
    float* qn = ws + WS_QN + q * 1600 + j * 64;
    for (int c = 0; c < 64; c++) qn[c] = (base[c * 25] - m) * rinv;
    ws[WS_QR + idx] = rinv;
    ws[WS_TP + idx] = pj + proj_b[0];
}

// TC-thread tiled matmul: O[m*SO+n] {=|+=} act( sum_k A[m*SA+k]*W[n*WN+k] + bias[n] )
// Tiles iterated by TC threads; a small leftover tile-set (<= TC scalar outputs) is
// handled one-output-per-thread.
template<int M, int N, int K, int TM, int TN, int SA, int WN, int SO, int VW,
         bool ADD, bool GELU, int TC>
__device__ __forceinline__ void mmw(const float* __restrict__ A, const float* __restrict__ W,
                                    const float* __restrict__ bias, float* __restrict__ O,
                                    int tid) {
    static_assert(M % TM == 0 && N % TN == 0, "tile");
    static_assert(K % VW == 0, "vec");
    constexpr int GM = M / TM, GN = N / TN, ITEMS = GM * GN;
    constexpr int FULL = (ITEMS / TC) * TC;
    constexpr int REMO = (ITEMS - FULL) * TM * TN;
    constexpr bool SCT = (ITEMS > FULL) && (FULL > 0) && (REMO <= TC);
    constexpr int LIM = SCT ? FULL : ITEMS;

    for (int v = tid; v < LIM; v += TC) {
        const int m0 = (v / GN) * TM, n0 = (v % GN) * TN;
        float acc[TM][TN];
#pragma unroll
        for (int a = 0; a < TM; a++)
#pragma unroll
            for (int c = 0; c < TN; c++) acc[a][c] = 0.f;

        if constexpr (VW == 4) {
#pragma unroll
            for (int k = 0; k < K; k += 4) {
                float4 av[TM], wv[TN];
#pragma unroll
                for (int a = 0; a < TM; a++) av[a] = *(const float4*)(A + (m0 + a) * SA + k);
#pragma unroll
                for (int c = 0; c < TN; c++) wv[c] = *(const float4*)(W + (n0 + c) * WN + k);
#pragma unroll
                for (int a = 0; a < TM; a++)
#pragma unroll
                    for (int c = 0; c < TN; c++) {
                        acc[a][c] += av[a].x * wv[c].x;
                        acc[a][c] += av[a].y * wv[c].y;
                        acc[a][c] += av[a].z * wv[c].z;
                        acc[a][c] += av[a].w * wv[c].w;
                    }
            }
        } else {
#pragma unroll 4
            for (int k = 0; k < K; k += 2) {
                float2 av[TM], wv[TN];
#pragma unroll
                for (int a = 0; a < TM; a++) av[a] = *(const float2*)(A + (m0 + a) * SA + k);
#pragma unroll
                for (int c = 0; c < TN; c++) wv[c] = *(const float2*)(W + (n0 + c) * WN + k);
#pragma unroll
                for (int a = 0; a < TM; a++)
#pragma unroll
                    for (int c = 0; c < TN; c++) {
                        acc[a][c] += av[a].x * wv[c].x;
                        acc[a][c] += av[a].y * wv[c].y;
                    }
            }
        }
#pragma unroll
        for (int a = 0; a < TM; a++)
#pragma unroll
            for (int c = 0; c < TN; c++) {
                int n = n0 + c;
                float r = acc[a][c] + (bias ? bias[n] : 0.f);
                if (GELU) r = 0.5f * r * (1.f + erff(r * 0.70710678118654752f));
                if (ADD) O[(m0 + a) * SO + n] += r; else O[(m0 + a) * SO + n] = r;
            }
    }
    if constexpr (SCT) {
        if (tid < REMO) {
            const int t = FULL + tid / (TM * TN), r0 = tid % (TM * TN);
            const int m = (t / GN) * TM + r0 / TN, n = (t % GN) * TN + r0 % TN;
            float acc = 0.f;
#pragma unroll 4
            for (int k = 0; k < K; k += 2) {
                float2 a2 = *(const float2*)(A + m * SA + k);
                float2 w2 = *(const float2*)(W + n * WN + k);
                acc += a2.x * w2.x;
                acc += a2.y * w2.y;
            }
            float r = acc + (bias ? bias[n] : 0.f);
            if (GELU) r = 0.5f * r * (1.f + erff(r * 0.70710678118654752f));
            if (ADD) O[m * SO + n] += r; else O[m * SO + n] = r;
        }
    }
}

__device__ __forceinline__ void ln_row(const float* __restrict__ x, float* __restrict__ h,
                                       const float* __restrict__ g, const float* __restrict__ bb) {
    float s = 0.f;
#pragma unroll
    for (int e = 0; e < 26; e++) s += x[e];
    float m = s * (1.f / 26.f);
    float vv = 0.f;
#pragma unroll
    for (int e = 0; e < 26; e++) { float d = x[e] - m; vv += d * d; }
    float r = rsqrtf(vv * (1.f / 26.f) + 1e-6f);
#pragma unroll
    for (int e = 0; e < 26; e++) h[e] = (x[e] - m) * r * g[e] + bb[e];
}

// One wavefront per (q,w) item; 4 items per 256-thread block; NO block barriers
// (wave-level WSYNC only). Per-item LDS region = 2560 floats (pad from 1952):
//   xm 0..650 | hm 650..1300 (ln out / oatt / P_q) | scr 1300..1950 (phase union) | pad
// Padding pins LDS/block at 40960 B -> exactly 4 blocks/CU by LDS, so the backend's
// occupancy target is 4 waves/EU (VGPR budget 128 — R5's body chose exactly 128
// unconstrained, so it fits). Launch bounds (256,4): 5 rounds of evidence show the
// 2nd arg acts as the effective waves/EU cap on this toolchain — (256,2) was
// silently pinning every variant at 8 waves/CU (23%).
__global__ void __launch_bounds__(256, 4)
fused_kernel(const float* __restrict__ qry, const float* __restrict__ ws,
             const float* __restrict__ pos_x, const float* __restrict__ pos_y,
             const float* __restrict__ qkv_w, const float* __restrict__ qkv_b,
             const float* __restrict__ attn_w, const float* __restrict__ attn_b,
             const float* __restrict__ ln1_g, const float* __restrict__ ln1_b,
             const float* __restrict__ ln2_g, const float* __restrict__ ln2_b,
             const float* __restrict__ fc1_w, const float* __restrict__ fc1_b,
             const float* __restrict__ fc2_w, const float* __restrict__ fc2_b,
             const float* __restrict__ dec_w, const float* __restrict__ dec_b,
             float* __restrict__ out) {
    __shared__ __align__(16) float lds[4 * 2560];
    const int wid = threadIdx.x >> 6, lane = threadIdx.x & 63;
    const int b = blockIdx.x * 4 + wid, q = b / WAYS, w = b % WAYS;

    float* xm  = lds + wid * 2560;
    float* hm  = xm + 650;
    float* scr = xm + 1300;

    const float* scg = ws + WS_SC + w * 1600;   // sc[i][c], stride 64
    const float* qng = ws + WS_QN + q * 1600;   // qn[j][c], stride 64

    const int h = lane / 25, ii = lane - h * 25;   // attention row id (lane<50)

    // corr[i][j] = sc_i . qn_j -> scr[i*25+j]
    mmw<25, 25, 64, 5, 1, 64, 64, 25, 4, false, false, 64>(scg, qng, nullptr, scr, lane);
    WSYNC();

    // x1: rows = qry tokens; [corr^T | tp] + pos
    for (int e = lane; e < 650; e += 64) {
        int t = e / 26, d = e - t * 26;
        float p = (d < 13) ? pos_x[(t % 5) * 13 + d] : pos_y[(t / 5) * 13 + (d - 13)];
        float base = (d < 25) ? scr[d * 25 + t] : ws[WS_TP + q * 25 + t];
        xm[e] = base + p;
    }
    WSYNC();

    for (int it = 0; it < 2; ++it) {
        // ln1
        if (lane < 25) ln_row(xm + lane * 26, hm + lane * 26, ln1_g, ln1_b);
        WSYNC();
        // ---- attention: q, k, v each computed into the SAME 650-float scr slot ----
        float qv[13], P[25], inv;
        // q pass
        mmw<25, 26, 26, 5, 2, 26, 26, 26, 2, false, false, 64>(hm, qkv_w, qkv_b, scr, lane);
        WSYNC();
        if (lane < 50) {
            const float* qb = scr + ii * 26 + h * 13;
#pragma unroll
            for (int k = 0; k < 13; k++) qv[k] = qb[k];
        }
        WSYNC();
        // k pass (overwrites q in scr; qv lives in regs)
        mmw<25, 26, 26, 5, 2, 26, 26, 26, 2, false, false, 64>(hm, qkv_w + 676, qkv_b + 26, scr, lane);
        WSYNC();
        if (lane < 50) {
            float mx = -1e30f;
#pragma unroll
            for (int j = 0; j < 25; j++) {
                const float* kb = scr + j * 26 + h * 13;   // broadcast within head
                float a = 0.f;
#pragma unroll
                for (int k = 0; k < 13; k++) a += qv[k] * kb[k];
                a *= 0.27735009811261457f;   // 13^-0.5
                P[j] = a; mx = fmaxf(mx, a);
            }
            float s = 0.f;
#pragma unroll
            for (int j = 0; j < 25; j++) { P[j] = __expf(P[j] - mx); s += P[j]; }
            inv = 1.f / s;
        }
        WSYNC();
        // v pass (overwrites k in scr; P,inv live in regs)
        mmw<25, 26, 26, 5, 2, 26, 26, 26, 2, false, false, 64>(hm, qkv_w + 1352, qkv_b + 52, scr, lane);
        WSYNC();
        if (lane < 50) {
            float o[13];
#pragma unroll
            for (int n = 0; n < 13; n++) o[n] = 0.f;
#pragma unroll
            for (int k = 0; k < 25; k++) {
                const float* vb = scr + k * 26 + h * 13;
                float p = P[k];
#pragma unroll
                for (int n = 0; n < 13; n++) o[n] += p * vb[n];
            }
            float* ob = hm + ii * 26 + h * 13;   // hm (ln rows) fully consumed by v pass
#pragma unroll
            for (int n = 0; n < 13; n++) ob[n] = o[n] * inv;
        }
        WSYNC();
        // attn proj + residual
        mmw<25, 26, 26, 5, 2, 26, 26, 26, 2, true, false, 64>(hm, attn_w, attn_b, xm, lane);
        WSYNC();
        if (lane < 25) ln_row(xm + lane * 26, hm + lane * 26, ln2_g, ln2_b);
        WSYNC();
        // MLP in four 26-wide quarters (hidden quarter fits the 650-float scr slot)
#pragma unroll
        for (int Qt = 0; Qt < 4; ++Qt) {
            mmw<25, 26, 26, 5, 2, 26, 26, 26, 2, false, true, 64>(hm, fc1_w + 676 * Qt,
                                                                  fc1_b + 26 * Qt, scr, lane);
            WSYNC();
            mmw<25, 26, 26, 5, 2, 26, 104, 26, 2, true, false, 64>(scr, fc2_w + 26 * Qt,
                                                                   Qt == 0 ? fc2_b : nullptr, xm, lane);
            WSYNC();
        }
        // dec -> scr[m*25+n]
        mmw<25, 25, 26, 5, 1, 26, 26, 25, 2, false, false, 64>(xm, dec_w, dec_b, scr, lane);
        WSYNC();
        if (it == 0) {
            // scr[d*25+t] += corr[t][d] = qn_d . sc_t  (== dec1 + corr in one buffer)
            mmw<25, 25, 64, 5, 1, 64, 64, 25, 4, true, false, 64>(qng, scg, nullptr, scr, lane);
            WSYNC();
            // x2: rows = spt tokens; [(dec1^T + corr) | sp] + pos
            for (int e = lane; e < 650; e += 64) {
                int t = e / 26, d = e - t * 26;
                float p = (d < 13) ? pos_x[(t % 5) * 13 + d] : pos_y[(t / 5) * 13 + (d - 13)];
                float base = (d < 25) ? scr[d * 25 + t] : ws[WS_SP + w * 25 + t];
                xm[e] = base + p;
            }
            WSYNC();
        }
    }

    // refined = dec2 + corr: scr[i*25+j] += sc_i . qn_j
    mmw<25, 25, 64, 5, 1, 64, 64, 25, 4, true, false, 64>(scg, qng, nullptr, scr, lane);
    WSYNC();

    // attn_s: per column j, gnorm+softmax over i -> P_s in xm (xm is dead)
    if (lane < 25) {
        int j = lane;
        float s = 0.f;
        for (int i = 0; i < 25; i++) s += scr[i * 25 + j];
        float m = s * 0.04f;
        float ss = 0.f;
        for (int i = 0; i < 25; i++) { float d = scr[i * 25 + j] - m; ss += d * d; }
        float rinv = rsqrtf(ss * (1.f / 24.f) + 1e-5f) * 0.2f;   // /T_ATTN
        float mx = -1e30f;
        for (int i = 0; i < 25; i++) { float z = (scr[i * 25 + j] - m) * rinv; xm[i * 25 + j] = z; mx = fmaxf(mx, z); }
        float se = 0.f;
        for (int i = 0; i < 25; i++) { float e2 = __expf(xm[i * 25 + j] - mx); xm[i * 25 + j] = e2; se += e2; }
        float iv = 1.f / se;
        for (int i = 0; i < 25; i++) xm[i * 25 + j] *= iv;
    }
    // attn_q: per row i, gnorm+softmax over j -> P_q in hm (hm is dead)
    if (lane < 25) {
        int i = lane;
        float s = 0.f;
        for (int j = 0; j < 25; j++) s += scr[i * 25 + j];
        float m = s * 0.04f;
        float ss = 0.f;
        for (int j = 0; j < 25; j++) { float d = scr[i * 25 + j] - m; ss += d * d; }
        float rinv = rsqrtf(ss * (1.f / 24.f) + 1e-5f) * 0.2f;
        float mx = -1e30f;
        for (int j = 0; j < 25; j++) { float z = (scr[i * 25 + j] - m) * rinv; hm[i * 25 + j] = z; mx = fmaxf(mx, z); }
        float se = 0.f;
        for (int j = 0; j < 25; j++) { float e2 = __expf(hm[i * 25 + j] - mx); hm[i * 25 + j] = e2; se += e2; }
        float iv = 1.f / se;
        for (int j = 0; j < 25; j++) hm[i * 25 + j] *= iv;
    }
    WSYNC();
    // asv -> scr[0..25), aqv -> scr[32..57)  (refined is dead now)
    if (lane < 25) {
        int i = lane; float s = 0.f;
        for (int j = 0; j < 25; j++) s += xm[i * 25 + j];
        scr[i] = s * 0.04f / ws[WS_RS + w * 25 + i];
    }
    if (lane < 25) {
        int j = lane; float s = 0.f;
        for (int i = 0; i < 25; i++) s += hm[i * 25 + j];
        scr[32 + j] = s * 0.04f / ws[WS_QR + q * 25 + j];
    }
    WSYNC();

    // pooled features per channel (lane = c, coalesced global reads) + cosine reduce
    {
        float sv = 0.f, qv2 = 0.f;
        const float* snb = scg + lane;
        for (int i = 0; i < 25; i++) sv += scr[i] * snb[i * 64];
        const float* qnb = qng + lane;
        for (int j = 0; j < 25; j++) qv2 += scr[32 + j] * qnb[j * 64];
        float d = sv * qv2, n1 = sv * sv, n2 = qv2 * qv2;
#pragma unroll
        for (int msk = 32; msk >= 1; msk >>= 1) {
            d  += __shfl_xor(d,  msk);
            n1 += __shfl_xor(n1, msk);
            n2 += __shfl_xor(n2, msk);
        }
        if (lane == 0) {
            n1 = fmaxf(sqrtf(n1), 1e-8f);
            n2 = fmaxf(sqrtf(n2), 1e-8f);
            out[b] = d / (n1 * n2) * 5.f;   // /TEMP
        }
    }
}

extern "C" void kernel_launch(void* const* d_in, const int* in_sizes, int n_in,
                              void* d_out, int out_size, void* d_ws, size_t ws_size,
                              hipStream_t stream) {
    const float* spt    = (const float*)d_in[0];
    const float* qry    = (const float*)d_in[1];
    const float* proj_w = (const float*)d_in[2];
    const float* proj_b = (const float*)d_in[3];
    const float* pos_x  = (const float*)d_in[4];
    const float* pos_y  = (const float*)d_in[5];
    const float* ln1_g  = (const float*)d_in[6];
    const float* ln1_b  = (const float*)d_in[7];
    const float* qkv_w  = (const float*)d_in[8];
    const float* qkv_b  = (const float*)d_in[9];
    const float* attn_w = (const float*)d_in[10];
    const float* attn_b = (const float*)d_in[11];
    const float* ln2_g  = (const float*)d_in[12];
    const float* ln2_b  = (const float*)d_in[13];
    const float* fc1_w  = (const float*)d_in[14];
    const float* fc1_b  = (const float*)d_in[15];
    const float* fc2_w  = (const float*)d_in[16];
    const float* fc2_b  = (const float*)d_in[17];
    const float* dec_w  = (const float*)d_in[18];
    const float* dec_b  = (const float*)d_in[19];
    float* ws  = (float*)d_ws;
    float* out = (float*)d_out;

    prep_spt<<<1, 128, 0, stream>>>(spt, proj_w, proj_b, ws);
    prep_qry<<<(NQN * 25 + 255) / 256, 256, 0, stream>>>(qry, proj_w, proj_b, ws);
    fused_kernel<<<NBATCH / 4, 256, 0, stream>>>(qry, ws, pos_x, pos_y, qkv_w, qkv_b, attn_w, attn_b,
                                                 ln1_g, ln1_b, ln2_g, ln2_b, fc1_w, fc1_b,
                                                 fc2_w, fc2_b, dec_w, dec_b, out);
}

// Round 7
// 1476.817 us; speedup vs baseline: 1.2503x; 1.2503x over previous
//
#include <hip/hip_runtime.h>
#include <math.h>

#define WAYS 5
#define NQN 4096
#define NBATCH (NQN*WAYS)

// workspace float offsets
#define WS_SC 0         // 5*25*64 spt centered*rinv (l2-normalized) [w][i][c]
#define WS_RS 8000      // 125 spt inv l2 norms
#define WS_SP 8125      // 125 spt proj
#define WS_QR 8250      // 102400 qry inv l2 norm [q][j]
#define WS_TP 110650    // 102400 qry proj [q][j]
#define WS_QN 213052    // 4096*25*64 qry centered*rinv (l2-normalized) [q][j][c] (16B aligned)

// wave-level phase fence: DS ops of one wave complete in order; waitcnt + compiler barrier
#define WSYNC() do { asm volatile("s_waitcnt lgkmcnt(0)" ::: "memory"); __builtin_amdgcn_wave_barrier(); } while(0)

__global__ void prep_spt(const float* __restrict__ spt, const float* __restrict__ proj_w,
                         const float* __restrict__ proj_b, float* __restrict__ ws) {
    int tid = threadIdx.x;
    if (tid >= 125) return;
    int w = tid / 25, i = tid % 25;
    const float* base = spt + w * 1600 + i;
    float s = 0.f;
    for (int c = 0; c < 64; c++) s += base[c * 25];
    float m = s * (1.f / 64.f);
    float ss = 0.f, pj = 0.f;
    for (int c = 0; c < 64; c++) {
        float v = base[c * 25] - m;
        ss += v * v; pj += v * proj_w[c];
    }
    float rinv = rsqrtf(ss + 1e-6f);
    for (int c = 0; c < 64; c++)
        ws[WS_SC + (w * 25 + i) * 64 + c] = (base[c * 25] - m) * rinv;
    ws[WS_RS + w * 25 + i] = rinv;
    ws[WS_SP + w * 25 + i] = pj + proj_b[0];
}

__global__ void prep_qry(const float* __restrict__ qry, const float* __restrict__ proj_w,
                         const float* __restrict__ proj_b, float* __restrict__ ws) {
    int idx = blockIdx.x * 256 + threadIdx.x;
    if (idx >= NQN * 25) return;
    int q = idx / 25, j = idx % 25;
    const float* base = qry + q * 1600 + j;
    float s = 0.f;
    for (int c = 0; c < 64; c++) s += base[c * 25];
    float m = s * (1.f / 64.f);
    float ss = 0.f, pj = 0.f;
    for (int c = 0; c < 64; c++) {
        float v = base[c * 25] - m;
        ss += v * v; pj += v * proj_w[c];
    }
    float rinv = rsqrtf(ss + 1e-6f);
    float* qn = ws + WS_QN + q * 1600 + j * 64;
    for (int c = 0; c < 64; c++) qn[c] = (base[c * 25] - m) * rinv;
    ws[WS_QR + idx] = rinv;
    ws[WS_TP + idx] = pj + proj_b[0];
}

// TC-thread tiled matmul: O[m*SO+n] {=|+=} act( sum_k A[m*SA+k]*W[n*WN+k] + bias[n] )
// Tiles iterated by TC threads; a small leftover tile-set (<= TC scalar outputs) is
// handled one-output-per-thread.
template<int M, int N, int K, int TM, int TN, int SA, int WN, int SO, int VW,
         bool ADD, bool GELU, int TC>
__device__ __forceinline__ void mmw(const float* __restrict__ A, const float* __restrict__ W,
                                    const float* __restrict__ bias, float* __restrict__ O,
                                    int tid) {
    static_assert(M % TM == 0 && N % TN == 0, "tile");
    static_assert(K % VW == 0, "vec");
    constexpr int GM = M / TM, GN = N / TN, ITEMS = GM * GN;
    constexpr int FULL = (ITEMS / TC) * TC;
    constexpr int REMO = (ITEMS - FULL) * TM * TN;
    constexpr bool SCT = (ITEMS > FULL) && (FULL > 0) && (REMO <= TC);
    constexpr int LIM = SCT ? FULL : ITEMS;

    for (int v = tid; v < LIM; v += TC) {
        const int m0 = (v / GN) * TM, n0 = (v % GN) * TN;
        float acc[TM][TN];
#pragma unroll
        for (int a = 0; a < TM; a++)
#pragma unroll
            for (int c = 0; c < TN; c++) acc[a][c] = 0.f;

        if constexpr (VW == 4) {
#pragma unroll
            for (int k = 0; k < K; k += 4) {
                float4 av[TM], wv[TN];
#pragma unroll
                for (int a = 0; a < TM; a++) av[a] = *(const float4*)(A + (m0 + a) * SA + k);
#pragma unroll
                for (int c = 0; c < TN; c++) wv[c] = *(const float4*)(W + (n0 + c) * WN + k);
#pragma unroll
                for (int a = 0; a < TM; a++)
#pragma unroll
                    for (int c = 0; c < TN; c++) {
                        acc[a][c] += av[a].x * wv[c].x;
                        acc[a][c] += av[a].y * wv[c].y;
                        acc[a][c] += av[a].z * wv[c].z;
                        acc[a][c] += av[a].w * wv[c].w;
                    }
            }
        } else {
#pragma unroll 4
            for (int k = 0; k < K; k += 2) {
                float2 av[TM], wv[TN];
#pragma unroll
                for (int a = 0; a < TM; a++) av[a] = *(const float2*)(A + (m0 + a) * SA + k);
#pragma unroll
                for (int c = 0; c < TN; c++) wv[c] = *(const float2*)(W + (n0 + c) * WN + k);
#pragma unroll
                for (int a = 0; a < TM; a++)
#pragma unroll
                    for (int c = 0; c < TN; c++) {
                        acc[a][c] += av[a].x * wv[c].x;
                        acc[a][c] += av[a].y * wv[c].y;
                    }
            }
        }
#pragma unroll
        for (int a = 0; a < TM; a++)
#pragma unroll
            for (int c = 0; c < TN; c++) {
                int n = n0 + c;
                float r = acc[a][c] + (bias ? bias[n] : 0.f);
                if (GELU) r = 0.5f * r * (1.f + erff(r * 0.70710678118654752f));
                if (ADD) O[(m0 + a) * SO + n] += r; else O[(m0 + a) * SO + n] = r;
            }
    }
    if constexpr (SCT) {
        if (tid < REMO) {
            const int t = FULL + tid / (TM * TN), r0 = tid % (TM * TN);
            const int m = (t / GN) * TM + r0 / TN, n = (t % GN) * TN + r0 % TN;
            float acc = 0.f;
#pragma unroll 4
            for (int k = 0; k < K; k += 2) {
                float2 a2 = *(const float2*)(A + m * SA + k);
                float2 w2 = *(const float2*)(W + n * WN + k);
                acc += a2.x * w2.x;
                acc += a2.y * w2.y;
            }
            float r = acc + (bias ? bias[n] : 0.f);
            if (GELU) r = 0.5f * r * (1.f + erff(r * 0.70710678118654752f));
            if (ADD) O[m * SO + n] += r; else O[m * SO + n] = r;
        }
    }
}

__device__ __forceinline__ void ln_row(const float* __restrict__ x, float* __restrict__ h,
                                       const float* __restrict__ g, const float* __restrict__ bb) {
    float s = 0.f;
#pragma unroll
    for (int e = 0; e < 26; e++) s += x[e];
    float m = s * (1.f / 26.f);
    float vv = 0.f;
#pragma unroll
    for (int e = 0; e < 26; e++) { float d = x[e] - m; vv += d * d; }
    float r = rsqrtf(vv * (1.f / 26.f) + 1e-6f);
#pragma unroll
    for (int e = 0; e < 26; e++) h[e] = (x[e] - m) * r * g[e] + bb[e];
}

// One wavefront per (q,w) item; 4 items per 256-thread block; NO block barriers
// (wave-level WSYNC only). Per-item LDS region = 3264 floats (13056 B):
//   xm 0..650 | hm 650..1300 (ln out / oatt / P_q) | scr 1300..3250 (phase union:
//     corr 625 | qkv [25][78] = 1950 (q@0,k@26,v@52; heads at +h*13) |
//     mlp-hid half [25][52]=1300 | dec/refined 625 | asv/aqv)
// Block LDS = 52224 B -> 3 blocks/CU by LDS = 12 waves/CU.
// __launch_bounds__(256,3): 6 rounds of evidence show achieved waves/EU == 2nd arg;
// (256,2) pinned at 8 waves/CU, (256,4) capped VGPR at 128 and spilled the ~128-reg
// body to scratch (R3/R6: VGPR 64, GB-scale hbm_bytes). Cap 3 -> VGPR budget ~168,
// body (~112, proven in R2 for this merged-qkv/single-phase-attn shape) fits clean.
__global__ void __launch_bounds__(256, 3)
fused_kernel(const float* __restrict__ qry, const float* __restrict__ ws,
             const float* __restrict__ pos_x, const float* __restrict__ pos_y,
             const float* __restrict__ qkv_w, const float* __restrict__ qkv_b,
             const float* __restrict__ attn_w, const float* __restrict__ attn_b,
             const float* __restrict__ ln1_g, const float* __restrict__ ln1_b,
             const float* __restrict__ ln2_g, const float* __restrict__ ln2_b,
             const float* __restrict__ fc1_w, const float* __restrict__ fc1_b,
             const float* __restrict__ fc2_w, const float* __restrict__ fc2_b,
             const float* __restrict__ dec_w, const float* __restrict__ dec_b,
             float* __restrict__ out) {
    __shared__ __align__(16) float lds[4 * 3264];
    const int wid = threadIdx.x >> 6, lane = threadIdx.x & 63;
    const int b = blockIdx.x * 4 + wid, q = b / WAYS, w = b % WAYS;

    float* xm  = lds + wid * 3264;
    float* hm  = xm + 650;
    float* scr = xm + 1300;

    const float* scg = ws + WS_SC + w * 1600;   // sc[i][c], stride 64
    const float* qng = ws + WS_QN + q * 1600;   // qn[j][c], stride 64

    const int h = lane / 25, ii = lane - h * 25;   // attention row id (lane<50)

    // corr[i][j] = sc_i . qn_j -> scr[i*25+j]
    mmw<25, 25, 64, 5, 1, 64, 64, 25, 4, false, false, 64>(scg, qng, nullptr, scr, lane);
    WSYNC();

    // x1: rows = qry tokens; [corr^T | tp] + pos
    for (int e = lane; e < 650; e += 64) {
        int t = e / 26, d = e - t * 26;
        float p = (d < 13) ? pos_x[(t % 5) * 13 + d] : pos_y[(t / 5) * 13 + (d - 13)];
        float base = (d < 25) ? scr[d * 25 + t] : ws[WS_TP + q * 25 + t];
        xm[e] = base + p;
    }
    WSYNC();

    for (int it = 0; it < 2; ++it) {
        // ln1
        if (lane < 25) ln_row(xm + lane * 26, hm + lane * 26, ln1_g, ln1_b);
        WSYNC();
        // qkv in ONE matmul into scr [25][78]: q@0..25, k@26..51, v@52..77 (head h at +h*13)
        mmw<25, 78, 26, 5, 3, 26, 26, 78, 2, false, false, 64>(hm, qkv_w, qkv_b, scr, lane);
        WSYNC();
        // fused attention, single phase: lane (h,ii) owns one score row fully in regs.
        // No register state crosses any mmw call (the R5/R6 VGPR-pressure source).
        // All 25 lanes of a head read the same k/v row address -> LDS broadcast.
        if (lane < 50) {
            const float* qb = scr + ii * 78 + h * 13;
            float qv[13];
#pragma unroll
            for (int k = 0; k < 13; k++) qv[k] = qb[k];
            float P[25];
            float mx = -1e30f;
#pragma unroll
            for (int j = 0; j < 25; j++) {
                const float* kb = scr + j * 78 + 26 + h * 13;
                float a = 0.f;
#pragma unroll
                for (int k = 0; k < 13; k++) a += qv[k] * kb[k];
                a *= 0.27735009811261457f;   // 13^-0.5
                P[j] = a; mx = fmaxf(mx, a);
            }
            float s = 0.f;
#pragma unroll
            for (int j = 0; j < 25; j++) { P[j] = __expf(P[j] - mx); s += P[j]; }
            float inv = 1.f / s;
            float o[13];
#pragma unroll
            for (int n = 0; n < 13; n++) o[n] = 0.f;
#pragma unroll
            for (int k = 0; k < 25; k++) {
                const float* vb = scr + k * 78 + 52 + h * 13;
                float p = P[k];
#pragma unroll
                for (int n = 0; n < 13; n++) o[n] += p * vb[n];
            }
            float* ob = hm + ii * 26 + h * 13;   // hm (ln1 rows) consumed by qkv mmw
#pragma unroll
            for (int n = 0; n < 13; n++) ob[n] = o[n] * inv;
        }
        WSYNC();
        // attn proj + residual
        mmw<25, 26, 26, 5, 2, 26, 26, 26, 2, true, false, 64>(hm, attn_w, attn_b, xm, lane);
        WSYNC();
        if (lane < 25) ln_row(xm + lane * 26, hm + lane * 26, ln2_g, ln2_b);
        WSYNC();
        // MLP in two 52-wide halves (hidden half = 1300 floats, fits scr)
        mmw<25, 52, 26, 5, 2, 26, 26, 52, 2, false, true, 64>(hm, fc1_w, fc1_b, scr, lane);
        WSYNC();
        mmw<25, 26, 52, 5, 2, 52, 104, 26, 2, true, false, 64>(scr, fc2_w, fc2_b, xm, lane);
        WSYNC();
        mmw<25, 52, 26, 5, 2, 26, 26, 52, 2, false, true, 64>(hm, fc1_w + 1352, fc1_b + 52, scr, lane);
        WSYNC();
        mmw<25, 26, 52, 5, 2, 52, 104, 26, 2, true, false, 64>(scr, fc2_w + 52, nullptr, xm, lane);
        WSYNC();
        // dec -> scr[m*25+n]
        mmw<25, 25, 26, 5, 1, 26, 26, 25, 2, false, false, 64>(xm, dec_w, dec_b, scr, lane);
        WSYNC();
        if (it == 0) {
            // scr[d*25+t] += corr[t][d] = qn_d . sc_t  (== dec1 + corr in one buffer)
            mmw<25, 25, 64, 5, 1, 64, 64, 25, 4, true, false, 64>(qng, scg, nullptr, scr, lane);
            WSYNC();
            // x2: rows = spt tokens; [(dec1^T + corr) | sp] + pos
            for (int e = lane; e < 650; e += 64) {
                int t = e / 26, d = e - t * 26;
                float p = (d < 13) ? pos_x[(t % 5) * 13 + d] : pos_y[(t / 5) * 13 + (d - 13)];
                float base = (d < 25) ? scr[d * 25 + t] : ws[WS_SP + w * 25 + t];
                xm[e] = base + p;
            }
            WSYNC();
        }
    }

    // refined = dec2 + corr: scr[i*25+j] += sc_i . qn_j
    mmw<25, 25, 64, 5, 1, 64, 64, 25, 4, true, false, 64>(scg, qng, nullptr, scr, lane);
    WSYNC();

    // attn_s: per column j, gnorm+softmax over i -> P_s in xm (xm is dead)
    if (lane < 25) {
        int j = lane;
        float s = 0.f;
        for (int i = 0; i < 25; i++) s += scr[i * 25 + j];
        float m = s * 0.04f;
        float ss = 0.f;
        for (int i = 0; i < 25; i++) { float d = scr[i * 25 + j] - m; ss += d * d; }
        float rinv = rsqrtf(ss * (1.f / 24.f) + 1e-5f) * 0.2f;   // /T_ATTN
        float mx = -1e30f;
        for (int i = 0; i < 25; i++) { float z = (scr[i * 25 + j] - m) * rinv; xm[i * 25 + j] = z; mx = fmaxf(mx, z); }
        float se = 0.f;
        for (int i = 0; i < 25; i++) { float e2 = __expf(xm[i * 25 + j] - mx); xm[i * 25 + j] = e2; se += e2; }
        float iv = 1.f / se;
        for (int i = 0; i < 25; i++) xm[i * 25 + j] *= iv;
    }
    // attn_q: per row i, gnorm+softmax over j -> P_q in hm (hm is dead)
    if (lane < 25) {
        int i = lane;
        float s = 0.f;
        for (int j = 0; j < 25; j++) s += scr[i * 25 + j];
        float m = s * 0.04f;
        float ss = 0.f;
        for (int j = 0; j < 25; j++) { float d = scr[i * 25 + j] - m; ss += d * d; }
        float rinv = rsqrtf(ss * (1.f / 24.f) + 1e-5f) * 0.2f;
        float mx = -1e30f;
        for (int j = 0; j < 25; j++) { float z = (scr[i * 25 + j] - m) * rinv; hm[i * 25 + j] = z; mx = fmaxf(mx, z); }
        float se = 0.f;
        for (int j = 0; j < 25; j++) { float e2 = __expf(hm[i * 25 + j] - mx); hm[i * 25 + j] = e2; se += e2; }
        float iv = 1.f / se;
        for (int j = 0; j < 25; j++) hm[i * 25 + j] *= iv;
    }
    WSYNC();
    // asv -> scr[0..25), aqv -> scr[32..57)  (refined is dead now)
    if (lane < 25) {
        int i = lane; float s = 0.f;
        for (int j = 0; j < 25; j++) s += xm[i * 25 + j];
        scr[i] = s * 0.04f / ws[WS_RS + w * 25 + i];
    }
    if (lane < 25) {
        int j = lane; float s = 0.f;
        for (int i = 0; i < 25; i++) s += hm[i * 25 + j];
        scr[32 + j] = s * 0.04f / ws[WS_QR + q * 25 + j];
    }
    WSYNC();

    // pooled features per channel (lane = c, coalesced global reads) + cosine reduce
    {
        float sv = 0.f, qv2 = 0.f;
        const float* snb = scg + lane;
        for (int i = 0; i < 25; i++) sv += scr[i] * snb[i * 64];
        const float* qnb = qng + lane;
        for (int j = 0; j < 25; j++) qv2 += scr[32 + j] * qnb[j * 64];
        float d = sv * qv2, n1 = sv * sv, n2 = qv2 * qv2;
#pragma unroll
        for (int msk = 32; msk >= 1; msk >>= 1) {
            d  += __shfl_xor(d,  msk);
            n1 += __shfl_xor(n1, msk);
            n2 += __shfl_xor(n2, msk);
        }
        if (lane == 0) {
            n1 = fmaxf(sqrtf(n1), 1e-8f);
            n2 = fmaxf(sqrtf(n2), 1e-8f);
            out[b] = d / (n1 * n2) * 5.f;   // /TEMP
        }
    }
}

extern "C" void kernel_launch(void* const* d_in, const int* in_sizes, int n_in,
                              void* d_out, int out_size, void* d_ws, size_t ws_size,
                              hipStream_t stream) {
    const float* spt    = (const float*)d_in[0];
    const float* qry    = (const float*)d_in[1];
    const float* proj_w = (const float*)d_in[2];
    const float* proj_b = (const float*)d_in[3];
    const float* pos_x  = (const float*)d_in[4];
    const float* pos_y  = (const float*)d_in[5];
    const float* ln1_g  = (const float*)d_in[6];
    const float* ln1_b  = (const float*)d_in[7];
    const float* qkv_w  = (const float*)d_in[8];
    const float* qkv_b  = (const float*)d_in[9];
    const float* attn_w = (const float*)d_in[10];
    const float* attn_b = (const float*)d_in[11];
    const float* ln2_g  = (const float*)d_in[12];
    const float* ln2_b  = (const float*)d_in[13];
    const float* fc1_w  = (const float*)d_in[14];
    const float* fc1_b  = (const float*)d_in[15];
    const float* fc2_w  = (const float*)d_in[16];
    const float* fc2_b  = (const float*)d_in[17];
    const float* dec_w  = (const float*)d_in[18];
    const float* dec_b  = (const float*)d_in[19];
    float* ws  = (float*)d_ws;
    float* out = (float*)d_out;

    prep_spt<<<1, 128, 0, stream>>>(spt, proj_w, proj_b, ws);
    prep_qry<<<(NQN * 25 + 255) / 256, 256, 0, stream>>>(qry, proj_w, proj_b, ws);
    fused_kernel<<<NBATCH / 4, 256, 0, stream>>>(qry, ws, pos_x, pos_y, qkv_w, qkv_b, attn_w, attn_b,
                                                 ln1_g, ln1_b, ln2_g, ln2_b, fc1_w, fc1_b,
                                                 fc2_w, fc2_b, dec_w, dec_b, out);
}

// Round 8
// 1445.703 us; speedup vs baseline: 1.2772x; 1.0215x over previous
//
#include <hip/hip_runtime.h>
#include <math.h>

#define WAYS 5
#define NQN 4096
#define NBATCH (NQN*WAYS)

// workspace float offsets
#define WS_SC 0         // 5*25*64 spt centered*rinv (l2-normalized) [w][i][c]
#define WS_RS 8000      // 125 spt inv l2 norms
#define WS_SP 8125      // 125 spt proj
#define WS_QR 8250      // 102400 qry inv l2 norm [q][j]
#define WS_TP 110650    // 102400 qry proj [q][j]
#define WS_QN 213052    // 4096*25*64 qry centered*rinv (l2-normalized) [q][j][c] (16B aligned)

// wave-level phase fence: DS ops of one wave complete in order; waitcnt + compiler barrier
#define WSYNC() do { asm volatile("s_waitcnt lgkmcnt(0)" ::: "memory"); __builtin_amdgcn_wave_barrier(); } while(0)

__global__ void prep_spt(const float* __restrict__ spt, const float* __restrict__ proj_w,
                         const float* __restrict__ proj_b, float* __restrict__ ws) {
    int tid = threadIdx.x;
    if (tid >= 125) return;
    int w = tid / 25, i = tid % 25;
    const float* base = spt + w * 1600 + i;
    float s = 0.f;
    for (int c = 0; c < 64; c++) s += base[c * 25];
    float m = s * (1.f / 64.f);
    float ss = 0.f, pj = 0.f;
    for (int c = 0; c < 64; c++) {
        float v = base[c * 25] - m;
        ss += v * v; pj += v * proj_w[c];
    }
    float rinv = rsqrtf(ss + 1e-6f);
    for (int c = 0; c < 64; c++)
        ws[WS_SC + (w * 25 + i) * 64 + c] = (base[c * 25] - m) * rinv;
    ws[WS_RS + w * 25 + i] = rinv;
    ws[WS_SP + w * 25 + i] = pj + proj_b[0];
}

__global__ void prep_qry(const float* __restrict__ qry, const float* __restrict__ proj_w,
                         const float* __restrict__ proj_b, float* __restrict__ ws) {
    int idx = blockIdx.x * 256 + threadIdx.x;
    if (idx >= NQN * 25) return;
    int q = idx / 25, j = idx % 25;
    const float* base = qry + q * 1600 + j;
    float s = 0.f;
    for (int c = 0; c < 64; c++) s += base[c * 25];
    float m = s * (1.f / 64.f);
    float ss = 0.f, pj = 0.f;
    for (int c = 0; c < 64; c++) {
        float v = base[c * 25] - m;
        ss += v * v; pj += v * proj_w[c];
    }
    float rinv = rsqrtf(ss + 1e-6f);
    float* qn = ws + WS_QN + q * 1600 + j * 64;
    for (int c = 0; c < 64; c++) qn[c] = (base[c * 25] - m) * rinv;
    ws[WS_QR + idx] = rinv;
    ws[WS_TP + idx] = pj + proj_b[0];
}

// TC-thread tiled matmul: O[m*SO+n] {=|+=} act( sum_k A[m*SA+k]*W[n*WN+k] + bias[n] )
// Tiles iterated by TC threads; a small leftover tile-set (<= TC scalar outputs) is
// handled one-output-per-thread.
template<int M, int N, int K, int TM, int TN, int SA, int WN, int SO, int VW,
         bool ADD, bool GELU, int TC>
__device__ __forceinline__ void mmw(const float* __restrict__ A, const float* __restrict__ W,
                                    const float* __restrict__ bias, float* __restrict__ O,
                                    int tid) {
    static_assert(M % TM == 0 && N % TN == 0, "tile");
    static_assert(K % VW == 0, "vec");
    constexpr int GM = M / TM, GN = N / TN, ITEMS = GM * GN;
    constexpr int FULL = (ITEMS / TC) * TC;
    constexpr int REMO = (ITEMS - FULL) * TM * TN;
    constexpr bool SCT = (ITEMS > FULL) && (FULL > 0) && (REMO <= TC);
    constexpr int LIM = SCT ? FULL : ITEMS;

    for (int v = tid; v < LIM; v += TC) {
        const int m0 = (v / GN) * TM, n0 = (v % GN) * TN;
        float acc[TM][TN];
#pragma unroll
        for (int a = 0; a < TM; a++)
#pragma unroll
            for (int c = 0; c < TN; c++) acc[a][c] = 0.f;

        if constexpr (VW == 4) {
#pragma unroll
            for (int k = 0; k < K; k += 4) {
                float4 av[TM], wv[TN];
#pragma unroll
                for (int a = 0; a < TM; a++) av[a] = *(const float4*)(A + (m0 + a) * SA + k);
#pragma unroll
                for (int c = 0; c < TN; c++) wv[c] = *(const float4*)(W + (n0 + c) * WN + k);
#pragma unroll
                for (int a = 0; a < TM; a++)
#pragma unroll
                    for (int c = 0; c < TN; c++) {
                        acc[a][c] += av[a].x * wv[c].x;
                        acc[a][c] += av[a].y * wv[c].y;
                        acc[a][c] += av[a].z * wv[c].z;
                        acc[a][c] += av[a].w * wv[c].w;
                    }
            }
        } else {
#pragma unroll 4
            for (int k = 0; k < K; k += 2) {
                float2 av[TM], wv[TN];
#pragma unroll
                for (int a = 0; a < TM; a++) av[a] = *(const float2*)(A + (m0 + a) * SA + k);
#pragma unroll
                for (int c = 0; c < TN; c++) wv[c] = *(const float2*)(W + (n0 + c) * WN + k);
#pragma unroll
                for (int a = 0; a < TM; a++)
#pragma unroll
                    for (int c = 0; c < TN; c++) {
                        acc[a][c] += av[a].x * wv[c].x;
                        acc[a][c] += av[a].y * wv[c].y;
                    }
            }
        }
#pragma unroll
        for (int a = 0; a < TM; a++)
#pragma unroll
            for (int c = 0; c < TN; c++) {
                int n = n0 + c;
                float r = acc[a][c] + (bias ? bias[n] : 0.f);
                if (GELU) r = 0.5f * r * (1.f + erff(r * 0.70710678118654752f));
                if (ADD) O[(m0 + a) * SO + n] += r; else O[(m0 + a) * SO + n] = r;
            }
    }
    if constexpr (SCT) {
        if (tid < REMO) {
            const int t = FULL + tid / (TM * TN), r0 = tid % (TM * TN);
            const int m = (t / GN) * TM + r0 / TN, n = (t % GN) * TN + r0 % TN;
            float acc = 0.f;
#pragma unroll 4
            for (int k = 0; k < K; k += 2) {
                float2 a2 = *(const float2*)(A + m * SA + k);
                float2 w2 = *(const float2*)(W + n * WN + k);
                acc += a2.x * w2.x;
                acc += a2.y * w2.y;
            }
            float r = acc + (bias ? bias[n] : 0.f);
            if (GELU) r = 0.5f * r * (1.f + erff(r * 0.70710678118654752f));
            if (ADD) O[m * SO + n] += r; else O[m * SO + n] = r;
        }
    }
}

__device__ __forceinline__ void ln_row(const float* __restrict__ x, float* __restrict__ h,
                                       const float* __restrict__ g, const float* __restrict__ bb) {
    float s = 0.f;
#pragma unroll
    for (int e = 0; e < 26; e++) s += x[e];
    float m = s * (1.f / 26.f);
    float vv = 0.f;
#pragma unroll
    for (int e = 0; e < 26; e++) { float d = x[e] - m; vv += d * d; }
    float r = rsqrtf(vv * (1.f / 26.f) + 1e-6f);
#pragma unroll
    for (int e = 0; e < 26; e++) h[e] = (x[e] - m) * r * g[e] + bb[e];
}

// One wavefront per (q,w) item; 4 items per 256-thread block; NO block barriers
// (wave-level WSYNC only). Per-item LDS region = 3264 floats (13056 B):
//   xm 0..650 | hm 650..1300 (ln out / P_s-head0 / P_q) | scr 1300..3250 (phase union:
//     corr 625 | qkv [25][78] (q@0,k@26,v@52; heads at +h*13) |
//     mlp-hid half [25][52]=1300 | dec/refined 625 | asv/aqv)
// ATTENTION STATE LIVES IN LDS, not registers (R7's 166 MB scratch spill came from
// qv[13]+P[25]+o[13] = 51 live floats/lane):
//   P head0 row i -> hm[i*26..+25)        (hm dead after qkv mmw consumed ln1 rows)
//   P head1 row i -> scr[i*78..+25)       (q-columns dead once qv is in registers)
//   oatt row i    -> scr[i*78+26..+52)    (k-columns dead after scoring)
// Lockstep within the uniform lane<50 branch + same-wave DS ordering make the
// overwrites safe; WSYNCs fence cross-lane visibility.
// Block LDS = 52224 B -> 3 blocks/CU = 12 waves/CU. __launch_bounds__(256,3):
// achieved waves/EU == 2nd arg (7/7 rounds); VGPR budget ~170, body now ~64-84
// with NO spill (max live ≈ qkv-mmw tile ~45).
__global__ void __launch_bounds__(256, 3)
fused_kernel(const float* __restrict__ qry, const float* __restrict__ ws,
             const float* __restrict__ pos_x, const float* __restrict__ pos_y,
             const float* __restrict__ qkv_w, const float* __restrict__ qkv_b,
             const float* __restrict__ attn_w, const float* __restrict__ attn_b,
             const float* __restrict__ ln1_g, const float* __restrict__ ln1_b,
             const float* __restrict__ ln2_g, const float* __restrict__ ln2_b,
             const float* __restrict__ fc1_w, const float* __restrict__ fc1_b,
             const float* __restrict__ fc2_w, const float* __restrict__ fc2_b,
             const float* __restrict__ dec_w, const float* __restrict__ dec_b,
             float* __restrict__ out) {
    __shared__ __align__(16) float lds[4 * 3264];
    const int wid = threadIdx.x >> 6, lane = threadIdx.x & 63;
    const int b = blockIdx.x * 4 + wid, q = b / WAYS, w = b % WAYS;

    float* xm  = lds + wid * 3264;
    float* hm  = xm + 650;
    float* scr = xm + 1300;

    const float* scg = ws + WS_SC + w * 1600;   // sc[i][c], stride 64
    const float* qng = ws + WS_QN + q * 1600;   // qn[j][c], stride 64

    const int h = lane / 25, ii = lane - h * 25;   // attention row id (lane<50)

    // corr[i][j] = sc_i . qn_j -> scr[i*25+j]
    mmw<25, 25, 64, 5, 1, 64, 64, 25, 4, false, false, 64>(scg, qng, nullptr, scr, lane);
    WSYNC();

    // x1: rows = qry tokens; [corr^T | tp] + pos
    for (int e = lane; e < 650; e += 64) {
        int t = e / 26, d = e - t * 26;
        float p = (d < 13) ? pos_x[(t % 5) * 13 + d] : pos_y[(t / 5) * 13 + (d - 13)];
        float base = (d < 25) ? scr[d * 25 + t] : ws[WS_TP + q * 25 + t];
        xm[e] = base + p;
    }
    WSYNC();

    for (int it = 0; it < 2; ++it) {
        // ln1
        if (lane < 25) ln_row(xm + lane * 26, hm + lane * 26, ln1_g, ln1_b);
        WSYNC();
        // qkv in ONE matmul into scr [25][78]: q@0..25, k@26..51, v@52..77 (head h at +h*13)
        mmw<25, 78, 26, 5, 3, 26, 26, 78, 2, false, false, 64>(hm, qkv_w, qkv_b, scr, lane);
        WSYNC();
        // fused attention, LDS-state variant. Lane (h,ii) owns one score row.
        // Only qv[13]+o[13] live in regs; P row lives in LDS (own-row access,
        // <=2-way bank conflicts). k/v reads are head-broadcast.
        if (lane < 50) {
            const float* qb = scr + ii * 78 + h * 13;
            float qv[13];
#pragma unroll
            for (int k = 0; k < 13; k++) qv[k] = qb[k];
            // P row storage: head0 -> hm (dead), head1 -> q-columns (dead after qv copy)
            float* Prow = h ? (scr + ii * 78) : (hm + ii * 26);
            float mx = -1e30f;
#pragma unroll
            for (int j = 0; j < 25; j++) {
                const float* kb = scr + j * 78 + 26 + h * 13;
                float a = 0.f;
#pragma unroll
                for (int k = 0; k < 13; k++) a += qv[k] * kb[k];
                a *= 0.27735009811261457f;   // 13^-0.5
                Prow[j] = a; mx = fmaxf(mx, a);
            }
            float s = 0.f;
#pragma unroll
            for (int j = 0; j < 25; j++) { float e2 = __expf(Prow[j] - mx); Prow[j] = e2; s += e2; }
            float inv = 1.f / s;
            float o[13];
#pragma unroll
            for (int n = 0; n < 13; n++) o[n] = 0.f;
#pragma unroll
            for (int k = 0; k < 25; k++) {
                const float* vb = scr + k * 78 + 52 + h * 13;
                float p = Prow[k];
#pragma unroll
                for (int n = 0; n < 13; n++) o[n] += p * vb[n];
            }
            // oatt -> k-columns (all k reads precede this in program order; lockstep)
            float* ob = scr + ii * 78 + 26 + h * 13;
#pragma unroll
            for (int n = 0; n < 13; n++) ob[n] = o[n] * inv;
        }
        WSYNC();
        // attn proj + residual; A = oatt in k-columns, stride 78
        mmw<25, 26, 26, 5, 2, 78, 26, 26, 2, true, false, 64>(scr + 26, attn_w, attn_b, xm, lane);
        WSYNC();
        if (lane < 25) ln_row(xm + lane * 26, hm + lane * 26, ln2_g, ln2_b);
        WSYNC();
        // MLP in two 52-wide halves (hidden half = 1300 floats, fits scr)
        mmw<25, 52, 26, 5, 2, 26, 26, 52, 2, false, true, 64>(hm, fc1_w, fc1_b, scr, lane);
        WSYNC();
        mmw<25, 26, 52, 5, 2, 52, 104, 26, 2, true, false, 64>(scr, fc2_w, fc2_b, xm, lane);
        WSYNC();
        mmw<25, 52, 26, 5, 2, 26, 26, 52, 2, false, true, 64>(hm, fc1_w + 1352, fc1_b + 52, scr, lane);
        WSYNC();
        mmw<25, 26, 52, 5, 2, 52, 104, 26, 2, true, false, 64>(scr, fc2_w + 52, nullptr, xm, lane);
        WSYNC();
        // dec -> scr[m*25+n]
        mmw<25, 25, 26, 5, 1, 26, 26, 25, 2, false, false, 64>(xm, dec_w, dec_b, scr, lane);
        WSYNC();
        if (it == 0) {
            // scr[d*25+t] += corr[t][d] = qn_d . sc_t  (== dec1 + corr in one buffer)
            mmw<25, 25, 64, 5, 1, 64, 64, 25, 4, true, false, 64>(qng, scg, nullptr, scr, lane);
            WSYNC();
            // x2: rows = spt tokens; [(dec1^T + corr) | sp] + pos
            for (int e = lane; e < 650; e += 64) {
                int t = e / 26, d = e - t * 26;
                float p = (d < 13) ? pos_x[(t % 5) * 13 + d] : pos_y[(t / 5) * 13 + (d - 13)];
                float base = (d < 25) ? scr[d * 25 + t] : ws[WS_SP + w * 25 + t];
                xm[e] = base + p;
            }
            WSYNC();
        }
    }

    // refined = dec2 + corr: scr[i*25+j] += sc_i . qn_j
    mmw<25, 25, 64, 5, 1, 64, 64, 25, 4, true, false, 64>(scg, qng, nullptr, scr, lane);
    WSYNC();

    // attn_s: per column j, gnorm+softmax over i -> P_s in xm (xm is dead)
    if (lane < 25) {
        int j = lane;
        float s = 0.f;
        for (int i = 0; i < 25; i++) s += scr[i * 25 + j];
        float m = s * 0.04f;
        float ss = 0.f;
        for (int i = 0; i < 25; i++) { float d = scr[i * 25 + j] - m; ss += d * d; }
        float rinv = rsqrtf(ss * (1.f / 24.f) + 1e-5f) * 0.2f;   // /T_ATTN
        float mx = -1e30f;
        for (int i = 0; i < 25; i++) { float z = (scr[i * 25 + j] - m) * rinv; xm[i * 25 + j] = z; mx = fmaxf(mx, z); }
        float se = 0.f;
        for (int i = 0; i < 25; i++) { float e2 = __expf(xm[i * 25 + j] - mx); xm[i * 25 + j] = e2; se += e2; }
        float iv = 1.f / se;
        for (int i = 0; i < 25; i++) xm[i * 25 + j] *= iv;
    }
    // attn_q: per row i, gnorm+softmax over j -> P_q in hm (hm is dead)
    if (lane < 25) {
        int i = lane;
        float s = 0.f;
        for (int j = 0; j < 25; j++) s += scr[i * 25 + j];
        float m = s * 0.04f;
        float ss = 0.f;
        for (int j = 0; j < 25; j++) { float d = scr[i * 25 + j] - m; ss += d * d; }
        float rinv = rsqrtf(ss * (1.f / 24.f) + 1e-5f) * 0.2f;
        float mx = -1e30f;
        for (int j = 0; j < 25; j++) { float z = (scr[i * 25 + j] - m) * rinv; hm[i * 25 + j] = z; mx = fmaxf(mx, z); }
        float se = 0.f;
        for (int j = 0; j < 25; j++) { float e2 = __expf(hm[i * 25 + j] - mx); hm[i * 25 + j] = e2; se += e2; }
        float iv = 1.f / se;
        for (int j = 0; j < 25; j++) hm[i * 25 + j] *= iv;
    }
    WSYNC();
    // asv -> scr[0..25), aqv -> scr[32..57)  (refined is dead now)
    if (lane < 25) {
        int i = lane; float s = 0.f;
        for (int j = 0; j < 25; j++) s += xm[i * 25 + j];
        scr[i] = s * 0.04f / ws[WS_RS + w * 25 + i];
    }
    if (lane < 25) {
        int j = lane; float s = 0.f;
        for (int i = 0; i < 25; i++) s += hm[i * 25 + j];
        scr[32 + j] = s * 0.04f / ws[WS_QR + q * 25 + j];
    }
    WSYNC();

    // pooled features per channel (lane = c, coalesced global reads) + cosine reduce
    {
        float sv = 0.f, qv2 = 0.f;
        const float* snb = scg + lane;
        for (int i = 0; i < 25; i++) sv += scr[i] * snb[i * 64];
        const float* qnb = qng + lane;
        for (int j = 0; j < 25; j++) qv2 += scr[32 + j] * qnb[j * 64];
        float d = sv * qv2, n1 = sv * sv, n2 = qv2 * qv2;
#pragma unroll
        for (int msk = 32; msk >= 1; msk >>= 1) {
            d  += __shfl_xor(d,  msk);
            n1 += __shfl_xor(n1, msk);
            n2 += __shfl_xor(n2, msk);
        }
        if (lane == 0) {
            n1 = fmaxf(sqrtf(n1), 1e-8f);
            n2 = fmaxf(sqrtf(n2), 1e-8f);
            out[b] = d / (n1 * n2) * 5.f;   // /TEMP
        }
    }
}

extern "C" void kernel_launch(void* const* d_in, const int* in_sizes, int n_in,
                              void* d_out, int out_size, void* d_ws, size_t ws_size,
                              hipStream_t stream) {
    const float* spt    = (const float*)d_in[0];
    const float* qry    = (const float*)d_in[1];
    const float* proj_w = (const float*)d_in[2];
    const float* proj_b = (const float*)d_in[3];
    const float* pos_x  = (const float*)d_in[4];
    const float* pos_y  = (const float*)d_in[5];
    const float* ln1_g  = (const float*)d_in[6];
    const float* ln1_b  = (const float*)d_in[7];
    const float* qkv_w  = (const float*)d_in[8];
    const float* qkv_b  = (const float*)d_in[9];
    const float* attn_w = (const float*)d_in[10];
    const float* attn_b = (const float*)d_in[11];
    const float* ln2_g  = (const float*)d_in[12];
    const float* ln2_b  = (const float*)d_in[13];
    const float* fc1_w  = (const float*)d_in[14];
    const float* fc1_b  = (const float*)d_in[15];
    const float* fc2_w  = (const float*)d_in[16];
    const float* fc2_b  = (const float*)d_in[17];
    const float* dec_w  = (const float*)d_in[18];
    const float* dec_b  = (const float*)d_in[19];
    float* ws  = (float*)d_ws;
    float* out = (float*)d_out;

    prep_spt<<<1, 128, 0, stream>>>(spt, proj_w, proj_b, ws);
    prep_qry<<<(NQN * 25 + 255) / 256, 256, 0, stream>>>(qry, proj_w, proj_b, ws);
    fused_kernel<<<NBATCH / 4, 256, 0, stream>>>(qry, ws, pos_x, pos_y, qkv_w, qkv_b, attn_w, attn_b,
                                                 ln1_g, ln1_b, ln2_g, ln2_b, fc1_w, fc1_b,
                                                 fc2_w, fc2_b, dec_w, dec_b, out);
}